// Round 4
// baseline (556.032 us; speedup 1.0000x reference)
//
#include <hip/hip_runtime.h>

#define HID 768
#define NL  17
#define BB  64
#define TT  512

#define ROWS  64         // rows per block
#define XCH   128        // K-chunk size
#define NCH   6          // HID / XCH
#define WCOLS 16         // cols per wave per chunk (128 / 8 waves)

// ===========================================================================
// Kernel 1: emissions = outputs @ fc_w^T + fc_b   (32768x768 @ 768^T x17)
// 512 threads (8 waves) per block, 64 rows. Per chunk: x staged to swizzled
// LDS (conflict-free lane=row b128 reads), w chunk staged to LDS and read at
// wave-uniform addresses (broadcast). Next chunk's global loads issued before
// compute. Grid 512 = exactly 2 blocks/CU resident (76.8 KB LDS).
// ===========================================================================
__global__ __launch_bounds__(512, 4) void emis_kernel(const float* __restrict__ x,
                                                      const float* __restrict__ w,
                                                      const float* __restrict__ bias,
                                                      float* __restrict__ y) {
    __shared__ float xs[ROWS * XCH];            // 32 KB, XOR-swizzled slots
    __shared__ float wlds[NL * XCH];            // 8.5 KB, linear (uniform reads)
    __shared__ float pacc[8][NL][ROWS + 1];     // 35.4 KB

    const int tid  = threadIdx.x;
    const int lane = tid & 63;
    const int wid  = tid >> 6;                  // wave id 0..7 (uniform)
    const size_t rowbase = (size_t)blockIdx.x * ROWS;

    // x staging assignment: row sr = tid/8, slot s2 = (tid&7) + 8*u2
    const int sr = tid >> 3;                    // 0..63
    const int sc = tid & 7;                     // 0..7

    float4 stx[4];
    float4 stw, stw2;

#define LOAD_CHUNK(c)                                                         \
    {                                                                         \
        const float* xb = x + (rowbase + sr) * HID + (c) * XCH;               \
        _Pragma("unroll")                                                     \
        for (int u2 = 0; u2 < 4; ++u2)                                        \
            stx[u2] = *reinterpret_cast<const float4*>(xb + (sc + 8 * u2) * 4); \
        stw = *reinterpret_cast<const float4*>(                               \
            w + (tid >> 5) * HID + (c) * XCH + (tid & 31) * 4);               \
        if (tid < 32)                                                         \
            stw2 = *reinterpret_cast<const float4*>(                          \
                w + 16 * HID + (c) * XCH + tid * 4);                          \
    }

#define STORE_CHUNK()                                                         \
    {                                                                         \
        _Pragma("unroll")                                                     \
        for (int u2 = 0; u2 < 4; ++u2) {                                      \
            const int s2 = sc + 8 * u2;                                       \
            const int ps = s2 ^ (sr & 7);                                     \
            *reinterpret_cast<float4*>(&xs[sr * XCH + ps * 4]) = stx[u2];     \
        }                                                                     \
        *reinterpret_cast<float4*>(&wlds[(tid >> 5) * XCH + (tid & 31) * 4]) = stw; \
        if (tid < 32)                                                         \
            *reinterpret_cast<float4*>(&wlds[16 * XCH + tid * 4]) = stw2;     \
    }

    float acc[NL];
#pragma unroll
    for (int k = 0; k < NL; ++k) acc[k] = 0.f;

    LOAD_CHUNK(0);

    for (int c = 0; c < NCH; ++c) {
        __syncthreads();                         // prior chunk's readers done
        STORE_CHUNK();
        __syncthreads();
        if (c + 1 < NCH) LOAD_CHUNK(c + 1);      // issue early; hides under compute

        // compute: lane = row, this wave's 16 cols of the chunk
        float4 xf[4];
#pragma unroll
        for (int u = 0; u < 4; ++u) {
            const int ps = (4 * wid + u) ^ (lane & 7);
            xf[u] = *reinterpret_cast<const float4*>(&xs[lane * XCH + ps * 4]);
        }
#pragma unroll
        for (int k = 0; k < NL; ++k) {
            const float4* wk = reinterpret_cast<const float4*>(&wlds[k * XCH + wid * WCOLS]);
            float s0 = 0.f, s1 = 0.f, s2 = 0.f, s3 = 0.f;
#pragma unroll
            for (int u = 0; u < 4; ++u) {
                const float4 wv = wk[u];         // uniform addr -> LDS broadcast
                s0 = fmaf(xf[u].x, wv.x, s0);
                s1 = fmaf(xf[u].y, wv.y, s1);
                s2 = fmaf(xf[u].z, wv.z, s2);
                s3 = fmaf(xf[u].w, wv.w, s3);
            }
            acc[k] += (s0 + s1) + (s2 + s3);
        }
    }

#pragma unroll
    for (int k = 0; k < NL; ++k) pacc[wid][k][lane] = acc[k];
    __syncthreads();

    for (int o = tid; o < ROWS * NL; o += 512) {
        const int r = o / NL, k = o - r * NL;
        float s = bias[k];
#pragma unroll
        for (int sp = 0; sp < 8; ++sp) s += pacc[sp][k][r];
        y[rowbase * NL + o] = s;
    }
#undef LOAD_CHUNK
#undef STORE_CHUNK
}

// ===========================================================================
// Kernel 2: CRF llh. One wave per batch, no LDS. Exp-domain scan; lane j<17
// streams em column j straight from global (L2/L3-hit), double-buffered 8
// steps ahead with exp applied at prefetch. Renorm = exponent extract+ldexp.
// ===========================================================================
__device__ __forceinline__ float bcast(float v, int i) {
    return __uint_as_float(__builtin_amdgcn_readlane(__float_as_uint(v), i));
}

#define CRF_BODY(eem, PN)  \
    { float q0, q1, q2, q3;                                               \
      q0 = bcast(p,  0) * et[0];  q1 = bcast(p,  1) * et[1];              \
      q2 = bcast(p,  2) * et[2];  q3 = bcast(p,  3) * et[3];              \
      q0 = fmaf(bcast(p,  4), et[4],  q0); q1 = fmaf(bcast(p,  5), et[5],  q1); \
      q2 = fmaf(bcast(p,  6), et[6],  q2); q3 = fmaf(bcast(p,  7), et[7],  q3); \
      q0 = fmaf(bcast(p,  8), et[8],  q0); q1 = fmaf(bcast(p,  9), et[9],  q1); \
      q2 = fmaf(bcast(p, 10), et[10], q2); q3 = fmaf(bcast(p, 11), et[11], q3); \
      q0 = fmaf(bcast(p, 12), et[12], q0); q1 = fmaf(bcast(p, 13), et[13], q1); \
      q2 = fmaf(bcast(p, 14), et[14], q2); q3 = fmaf(bcast(p, 15), et[15], q3); \
      q0 = fmaf(bcast(p, 16), et[16], q0);                                \
      PN = ((q0 + q1) + (q2 + q3)) * (eem); }

#define CRF_STEP(eem)      { float pn_; CRF_BODY(eem, pn_); p = pn_; }
#define CRF_STEPG(eem, tt) { float pn_; CRF_BODY(eem, pn_); p = ((tt) < len) ? pn_ : p; }

__global__ __launch_bounds__(64) void crf_kernel(const float* __restrict__ emis,
                                                 const float* __restrict__ st_,
                                                 const float* __restrict__ en_,
                                                 const float* __restrict__ tr_,
                                                 const int* __restrict__ labels,
                                                 const int* __restrict__ mask,
                                                 float* __restrict__ llh) {
    const int b = blockIdx.x;
    const int l = threadIdx.x;
    const float* eb = emis + (size_t)b * TT * NL;
    const int*   lb = labels + b * TT;

    // ---- sequence length (prefix mask) ----
    int lenp = 0;
#pragma unroll
    for (int m = 0; m < 8; ++m) lenp += (mask[b * TT + l + 64 * m] != 0);
#pragma unroll
    for (int off = 32; off; off >>= 1) lenp += __shfl_down(lenp, off);
    const int len = __shfl(lenp, 0);

    // ---- numerator ----
    float np = 0.f;
#pragma unroll
    for (int m = 0; m < 8; ++m) {
        const int t = l + 64 * m;
        int tag = lb[t]; if ((unsigned)tag >= NL) tag = 0;
        if (t < len) {
            if (t == 0) {
                np += st_[tag] + eb[tag];
            } else {
                int tp = lb[t - 1]; if ((unsigned)tp >= NL) tp = 0;
                np += tr_[tp * NL + tag] + eb[t * NL + tag];
            }
            if (t == len - 1) np += en_[tag];
        }
    }
#pragma unroll
    for (int off = 32; off; off >>= 1) np += __shfl_down(np, off);
    const float num = __shfl(np, 0);

    // ---- denominator: exp-domain forward scan ----
    const bool act = (l < NL);
    const int  j   = act ? l : 0;

    float et[NL];
#pragma unroll
    for (int i = 0; i < NL; ++i) et[i] = act ? __expf(tr_[i * NL + j]) : 0.f;

    float p = act ? __expf(st_[j] + eb[j]) : 0.f;
    int   Mi = 0;

    float cur[8];
#pragma unroll
    for (int i = 0; i < 8; ++i) cur[i] = __expf(eb[(1 + i) * NL + j]);

    for (int t0 = 1; t0 < len; t0 += 8) {
        float nx[8];
#pragma unroll
        for (int i = 0; i < 8; ++i) {
            int tn = t0 + 8 + i; tn = (tn < TT) ? tn : (TT - 1);
            nx[i] = eb[tn * NL + j];             // issue; consumed next group
        }
        if (t0 + 8 <= len) {
            CRF_STEP(cur[0]); CRF_STEP(cur[1]); CRF_STEP(cur[2]); CRF_STEP(cur[3]);
            CRF_STEP(cur[4]); CRF_STEP(cur[5]); CRF_STEP(cur[6]); CRF_STEP(cur[7]);
        } else {
            CRF_STEPG(cur[0], t0 + 0); CRF_STEPG(cur[1], t0 + 1);
            CRF_STEPG(cur[2], t0 + 2); CRF_STEPG(cur[3], t0 + 3);
            CRF_STEPG(cur[4], t0 + 4); CRF_STEPG(cur[5], t0 + 5);
            CRF_STEPG(cur[6], t0 + 6); CRF_STEPG(cur[7], t0 + 7);
        }
        // renorm by p0 via exponent extraction (no log/rcp on critical path)
        const unsigned pb = (unsigned)__builtin_amdgcn_readlane((int)__float_as_uint(p), 0);
        const int e = (int)(pb >> 23) - 127;
        Mi += e;
        p = ldexpf(p, -e);
#pragma unroll
        for (int i = 0; i < 8; ++i) cur[i] = __expf(nx[i]);
    }

    float v = act ? p * __expf(en_[j]) : 0.f;
#pragma unroll
    for (int off = 32; off; off >>= 1) v += __shfl_down(v, off);

    if (l == 0) {
        const float denom = (float)Mi * 0.6931471805599453f + __logf(v);
        llh[b] = num - denom;
    }
}

// ===========================================================================
// Kernel 3: loss = -mean(llh)
// ===========================================================================
__global__ __launch_bounds__(64) void loss_kernel(const float* __restrict__ llh,
                                                  float* __restrict__ loss) {
    float v = llh[threadIdx.x];
#pragma unroll
    for (int off = 32; off; off >>= 1) v += __shfl_down(v, off);
    if (threadIdx.x == 0) loss[0] = -(v * (1.0f / BB));
}

// ===========================================================================
extern "C" void kernel_launch(void* const* d_in, const int* in_sizes, int n_in,
                              void* d_out, int out_size, void* d_ws, size_t ws_size,
                              hipStream_t stream) {
    const float* outputs = (const float*)d_in[0];
    const float* fc_w    = (const float*)d_in[1];
    const float* fc_b    = (const float*)d_in[2];
    const float* start_t = (const float*)d_in[3];
    const float* end_t   = (const float*)d_in[4];
    const float* trans   = (const float*)d_in[5];
    const int*   labels  = (const int*)d_in[6];
    const int*   mask    = (const int*)d_in[7];

    float* emis = (float*)d_out;
    float* loss = emis + (size_t)BB * TT * NL;
    float* llh  = (float*)d_ws;

    emis_kernel<<<(BB * TT) / ROWS, 512, 0, stream>>>(outputs, fc_w, fc_b, emis);
    crf_kernel<<<BB, 64, 0, stream>>>(emis, start_t, end_t, trans, labels, mask, llh);
    loss_kernel<<<1, 64, 0, stream>>>(llh, loss);
}

// Round 5
// 177.820 us; speedup vs baseline: 3.1269x; 3.1269x over previous
//
#include <hip/hip_runtime.h>

#define HID 768
#define NL  17
#define BB  64
#define TT  512

#define ROWS  64         // rows per block
#define XCH   128        // K-chunk size
#define NCH   6          // HID / XCH
#define WCOLS 16         // cols per wave per chunk (128 / 8 waves)

// ===========================================================================
// Kernel 1: emissions = outputs @ fc_w^T + fc_b   (32768x768 @ 768^T x17)
// 512 threads (8 waves) per block, 64 rows. Per chunk: x staged to swizzled
// LDS (conflict-free lane=row b128 reads), w chunk staged to LDS and read at
// wave-uniform addresses (broadcast). Next chunk's global loads issued before
// compute. Grid 512 = exactly 2 blocks/CU resident (77 KB LDS).
// NOTE: no 2nd __launch_bounds__ arg — hipcc treats it as min-BLOCKS/CU and
// caps VGPR (R3: capped to 64 -> ~1 GB scratch spill, 546 us).
// ===========================================================================
__global__ __launch_bounds__(512) void emis_kernel(const float* __restrict__ x,
                                                   const float* __restrict__ w,
                                                   const float* __restrict__ bias,
                                                   float* __restrict__ y) {
    __shared__ float xs[ROWS * XCH];            // 32 KB, XOR-swizzled slots
    __shared__ float wlds[NL * XCH];            // 8.5 KB, linear (uniform reads)
    __shared__ float pacc[8][NL][ROWS + 1];     // 35.4 KB

    const int tid  = threadIdx.x;
    const int lane = tid & 63;
    const int wid  = tid >> 6;                  // wave id 0..7 (uniform)
    const size_t rowbase = (size_t)blockIdx.x * ROWS;

    // x staging assignment: row sr = tid/8, slot s2 = (tid&7) + 8*u2
    const int sr = tid >> 3;                    // 0..63
    const int sc = tid & 7;                     // 0..7

    float4 stx[4];
    float4 stw, stw2;

#define LOAD_CHUNK(c)                                                         \
    {                                                                         \
        const float* xb = x + (rowbase + sr) * HID + (c) * XCH;               \
        _Pragma("unroll")                                                     \
        for (int u2 = 0; u2 < 4; ++u2)                                        \
            stx[u2] = *reinterpret_cast<const float4*>(xb + (sc + 8 * u2) * 4); \
        stw = *reinterpret_cast<const float4*>(                               \
            w + (tid >> 5) * HID + (c) * XCH + (tid & 31) * 4);               \
        if (tid < 32)                                                         \
            stw2 = *reinterpret_cast<const float4*>(                          \
                w + 16 * HID + (c) * XCH + tid * 4);                          \
    }

#define STORE_CHUNK()                                                         \
    {                                                                         \
        _Pragma("unroll")                                                     \
        for (int u2 = 0; u2 < 4; ++u2) {                                      \
            const int s2 = sc + 8 * u2;                                       \
            const int ps = s2 ^ (sr & 7);                                     \
            *reinterpret_cast<float4*>(&xs[sr * XCH + ps * 4]) = stx[u2];     \
        }                                                                     \
        *reinterpret_cast<float4*>(&wlds[(tid >> 5) * XCH + (tid & 31) * 4]) = stw; \
        if (tid < 32)                                                         \
            *reinterpret_cast<float4*>(&wlds[16 * XCH + tid * 4]) = stw2;     \
    }

    float acc[NL];
#pragma unroll
    for (int k = 0; k < NL; ++k) acc[k] = 0.f;

    LOAD_CHUNK(0);

    for (int c = 0; c < NCH; ++c) {
        __syncthreads();                         // prior chunk's readers done
        STORE_CHUNK();
        __syncthreads();
        if (c + 1 < NCH) LOAD_CHUNK(c + 1);      // issue early; hides under compute

        // compute: lane = row, this wave's 16 cols of the chunk
        float4 xf[4];
#pragma unroll
        for (int u = 0; u < 4; ++u) {
            const int ps = (4 * wid + u) ^ (lane & 7);
            xf[u] = *reinterpret_cast<const float4*>(&xs[lane * XCH + ps * 4]);
        }
#pragma unroll
        for (int k = 0; k < NL; ++k) {
            const float4* wk = reinterpret_cast<const float4*>(&wlds[k * XCH + wid * WCOLS]);
            float s0 = 0.f, s1 = 0.f, s2 = 0.f, s3 = 0.f;
#pragma unroll
            for (int u = 0; u < 4; ++u) {
                const float4 wv = wk[u];         // uniform addr -> LDS broadcast
                s0 = fmaf(xf[u].x, wv.x, s0);
                s1 = fmaf(xf[u].y, wv.y, s1);
                s2 = fmaf(xf[u].z, wv.z, s2);
                s3 = fmaf(xf[u].w, wv.w, s3);
            }
            acc[k] += (s0 + s1) + (s2 + s3);
        }
    }

#pragma unroll
    for (int k = 0; k < NL; ++k) pacc[wid][k][lane] = acc[k];
    __syncthreads();

    for (int o = tid; o < ROWS * NL; o += 512) {
        const int r = o / NL, k = o - r * NL;
        float s = bias[k];
#pragma unroll
        for (int sp = 0; sp < 8; ++sp) s += pacc[sp][k][r];
        y[rowbase * NL + o] = s;
    }
#undef LOAD_CHUNK
#undef STORE_CHUNK
}

// ===========================================================================
// Kernel 2: CRF llh. One wave per batch, no LDS. Exp-domain scan; lane j<17
// streams em column j straight from global (L2/L3-hit), double-buffered 8
// steps ahead with exp applied at prefetch. Renorm = exponent extract+ldexp.
// ===========================================================================
__device__ __forceinline__ float bcast(float v, int i) {
    return __uint_as_float(__builtin_amdgcn_readlane(__float_as_uint(v), i));
}

#define CRF_BODY(eem, PN)  \
    { float q0, q1, q2, q3;                                               \
      q0 = bcast(p,  0) * et[0];  q1 = bcast(p,  1) * et[1];              \
      q2 = bcast(p,  2) * et[2];  q3 = bcast(p,  3) * et[3];              \
      q0 = fmaf(bcast(p,  4), et[4],  q0); q1 = fmaf(bcast(p,  5), et[5],  q1); \
      q2 = fmaf(bcast(p,  6), et[6],  q2); q3 = fmaf(bcast(p,  7), et[7],  q3); \
      q0 = fmaf(bcast(p,  8), et[8],  q0); q1 = fmaf(bcast(p,  9), et[9],  q1); \
      q2 = fmaf(bcast(p, 10), et[10], q2); q3 = fmaf(bcast(p, 11), et[11], q3); \
      q0 = fmaf(bcast(p, 12), et[12], q0); q1 = fmaf(bcast(p, 13), et[13], q1); \
      q2 = fmaf(bcast(p, 14), et[14], q2); q3 = fmaf(bcast(p, 15), et[15], q3); \
      q0 = fmaf(bcast(p, 16), et[16], q0);                                \
      PN = ((q0 + q1) + (q2 + q3)) * (eem); }

#define CRF_STEP(eem)      { float pn_; CRF_BODY(eem, pn_); p = pn_; }
#define CRF_STEPG(eem, tt) { float pn_; CRF_BODY(eem, pn_); p = ((tt) < len) ? pn_ : p; }

__global__ __launch_bounds__(64) void crf_kernel(const float* __restrict__ emis,
                                                 const float* __restrict__ st_,
                                                 const float* __restrict__ en_,
                                                 const float* __restrict__ tr_,
                                                 const int* __restrict__ labels,
                                                 const int* __restrict__ mask,
                                                 float* __restrict__ llh) {
    const int b = blockIdx.x;
    const int l = threadIdx.x;
    const float* eb = emis + (size_t)b * TT * NL;
    const int*   lb = labels + b * TT;

    // ---- sequence length (prefix mask) ----
    int lenp = 0;
#pragma unroll
    for (int m = 0; m < 8; ++m) lenp += (mask[b * TT + l + 64 * m] != 0);
#pragma unroll
    for (int off = 32; off; off >>= 1) lenp += __shfl_down(lenp, off);
    const int len = __shfl(lenp, 0);

    // ---- numerator ----
    float np = 0.f;
#pragma unroll
    for (int m = 0; m < 8; ++m) {
        const int t = l + 64 * m;
        int tag = lb[t]; if ((unsigned)tag >= NL) tag = 0;
        if (t < len) {
            if (t == 0) {
                np += st_[tag] + eb[tag];
            } else {
                int tp = lb[t - 1]; if ((unsigned)tp >= NL) tp = 0;
                np += tr_[tp * NL + tag] + eb[t * NL + tag];
            }
            if (t == len - 1) np += en_[tag];
        }
    }
#pragma unroll
    for (int off = 32; off; off >>= 1) np += __shfl_down(np, off);
    const float num = __shfl(np, 0);

    // ---- denominator: exp-domain forward scan ----
    const bool act = (l < NL);
    const int  j   = act ? l : 0;

    float et[NL];
#pragma unroll
    for (int i = 0; i < NL; ++i) et[i] = act ? __expf(tr_[i * NL + j]) : 0.f;

    float p = act ? __expf(st_[j] + eb[j]) : 0.f;
    int   Mi = 0;

    float cur[8];
#pragma unroll
    for (int i = 0; i < 8; ++i) cur[i] = __expf(eb[(1 + i) * NL + j]);

    for (int t0 = 1; t0 < len; t0 += 8) {
        float nx[8];
#pragma unroll
        for (int i = 0; i < 8; ++i) {
            int tn = t0 + 8 + i; tn = (tn < TT) ? tn : (TT - 1);
            nx[i] = eb[tn * NL + j];             // issue; consumed next group
        }
        if (t0 + 8 <= len) {
            CRF_STEP(cur[0]); CRF_STEP(cur[1]); CRF_STEP(cur[2]); CRF_STEP(cur[3]);
            CRF_STEP(cur[4]); CRF_STEP(cur[5]); CRF_STEP(cur[6]); CRF_STEP(cur[7]);
        } else {
            CRF_STEPG(cur[0], t0 + 0); CRF_STEPG(cur[1], t0 + 1);
            CRF_STEPG(cur[2], t0 + 2); CRF_STEPG(cur[3], t0 + 3);
            CRF_STEPG(cur[4], t0 + 4); CRF_STEPG(cur[5], t0 + 5);
            CRF_STEPG(cur[6], t0 + 6); CRF_STEPG(cur[7], t0 + 7);
        }
        // renorm by p0 via exponent extraction (no log/rcp on critical path)
        const unsigned pb = (unsigned)__builtin_amdgcn_readlane((int)__float_as_uint(p), 0);
        const int e = (int)(pb >> 23) - 127;
        Mi += e;
        p = ldexpf(p, -e);
#pragma unroll
        for (int i = 0; i < 8; ++i) cur[i] = __expf(nx[i]);
    }

    float v = act ? p * __expf(en_[j]) : 0.f;
#pragma unroll
    for (int off = 32; off; off >>= 1) v += __shfl_down(v, off);

    if (l == 0) {
        const float denom = (float)Mi * 0.6931471805599453f + __logf(v);
        llh[b] = num - denom;
    }
}

// ===========================================================================
// Kernel 3: loss = -mean(llh)
// ===========================================================================
__global__ __launch_bounds__(64) void loss_kernel(const float* __restrict__ llh,
                                                  float* __restrict__ loss) {
    float v = llh[threadIdx.x];
#pragma unroll
    for (int off = 32; off; off >>= 1) v += __shfl_down(v, off);
    if (threadIdx.x == 0) loss[0] = -(v * (1.0f / BB));
}

// ===========================================================================
extern "C" void kernel_launch(void* const* d_in, const int* in_sizes, int n_in,
                              void* d_out, int out_size, void* d_ws, size_t ws_size,
                              hipStream_t stream) {
    const float* outputs = (const float*)d_in[0];
    const float* fc_w    = (const float*)d_in[1];
    const float* fc_b    = (const float*)d_in[2];
    const float* start_t = (const float*)d_in[3];
    const float* end_t   = (const float*)d_in[4];
    const float* trans   = (const float*)d_in[5];
    const int*   labels  = (const int*)d_in[6];
    const int*   mask    = (const int*)d_in[7];

    float* emis = (float*)d_out;
    float* loss = emis + (size_t)BB * TT * NL;
    float* llh  = (float*)d_ws;

    emis_kernel<<<(BB * TT) / ROWS, 512, 0, stream>>>(outputs, fc_w, fc_b, emis);
    crf_kernel<<<BB, 64, 0, stream>>>(emis, start_t, end_t, trans, labels, mask, llh);
    loss_kernel<<<1, 64, 0, stream>>>(llh, loss);
}

// Round 6
// 124.444 us; speedup vs baseline: 4.4681x; 1.4289x over previous
//
#include <hip/hip_runtime.h>

#define HID 768
#define NL  17
#define BB  64
#define TT  512

// ===========================================================================
// Kernel 1: emissions = outputs @ fc_w^T + fc_b   (32768x768 @ 768^T x 17)
// Split-8 structure (R1-proven, no spill): 512 thr = 8 waves, 64 rows/block.
// Wave s owns K-slice [96s, 96s+96); lane = row (per-lane row streams are
// line-efficient; w addresses wave-uniform -> s_load). x batches of 24 floats
// double-buffered so HBM latency hides under the 408-FMA batch body.
// LDS only for the split-K partial reduce (35.4 KB -> 2 blocks/CU, 16 w/CU).
// ===========================================================================
__global__ __launch_bounds__(512) void emis_kernel(const float* __restrict__ x,
                                                   const float* __restrict__ w,
                                                   const float* __restrict__ bias,
                                                   float* __restrict__ y) {
    __shared__ float pacc[8][NL][65];          // 35.4 KB

    const int tid  = threadIdx.x;
    const int lane = tid & 63;
    const int wid  = tid >> 6;                 // K-slice id 0..7
    const size_t rowbase = (size_t)blockIdx.x * 64;
    const float* rp = x + (rowbase + lane) * HID + wid * 96;
    const float* wb = w + wid * 96;

    float acc[NL];
#pragma unroll
    for (int k = 0; k < NL; ++k) acc[k] = 0.f;

    float4 ra[6], rb[6];

#define LOADB(dst, bt)                                                        \
    _Pragma("unroll")                                                         \
    for (int u = 0; u < 6; ++u)                                               \
        dst[u] = *reinterpret_cast<const float4*>(rp + (bt) * 24 + u * 4);

#define FMAB(src, bt)                                                         \
    _Pragma("unroll")                                                         \
    for (int k = 0; k < NL; ++k) {                                            \
        const float* wk = wb + k * HID + (bt) * 24;                           \
        float s0 = 0.f, s1 = 0.f, s2 = 0.f, s3 = 0.f;                         \
        _Pragma("unroll")                                                     \
        for (int u = 0; u < 6; ++u) {                                         \
            const float4 wv = *reinterpret_cast<const float4*>(wk + u * 4);   \
            s0 = fmaf(src[u].x, wv.x, s0);                                    \
            s1 = fmaf(src[u].y, wv.y, s1);                                    \
            s2 = fmaf(src[u].z, wv.z, s2);                                    \
            s3 = fmaf(src[u].w, wv.w, s3);                                    \
        }                                                                     \
        acc[k] += (s0 + s1) + (s2 + s3);                                      \
    }

    LOADB(ra, 0);                              // prologue
    LOADB(rb, 1); FMAB(ra, 0);                 // issue next, compute current
    LOADB(ra, 2); FMAB(rb, 1);
    LOADB(rb, 3); FMAB(ra, 2);
    FMAB(rb, 3);

#undef LOADB
#undef FMAB

#pragma unroll
    for (int k = 0; k < NL; ++k) pacc[wid][k][lane] = acc[k];
    __syncthreads();

    // reduce 8 partials; outputs contiguous per block: y[blk*1088 + o]
    for (int o = tid; o < 64 * NL; o += 512) {
        const int r = o / NL, k = o - r * NL;
        float s = bias[k];
#pragma unroll
        for (int sp = 0; sp < 8; ++sp) s += pacc[sp][k][r];
        y[rowbase * NL + o] = s;
    }
}

// ===========================================================================
// Kernel 2: CRF llh. One wave per batch, no LDS. Exp-domain scan; lane j<17
// streams em column j straight from global (L2/L3-hit), double-buffered 8
// steps ahead with exp applied at prefetch. Renorm = exponent extract+ldexp.
// ===========================================================================
__device__ __forceinline__ float bcast(float v, int i) {
    return __uint_as_float(__builtin_amdgcn_readlane(__float_as_uint(v), i));
}

#define CRF_BODY(eem, PN)  \
    { float q0, q1, q2, q3;                                               \
      q0 = bcast(p,  0) * et[0];  q1 = bcast(p,  1) * et[1];              \
      q2 = bcast(p,  2) * et[2];  q3 = bcast(p,  3) * et[3];              \
      q0 = fmaf(bcast(p,  4), et[4],  q0); q1 = fmaf(bcast(p,  5), et[5],  q1); \
      q2 = fmaf(bcast(p,  6), et[6],  q2); q3 = fmaf(bcast(p,  7), et[7],  q3); \
      q0 = fmaf(bcast(p,  8), et[8],  q0); q1 = fmaf(bcast(p,  9), et[9],  q1); \
      q2 = fmaf(bcast(p, 10), et[10], q2); q3 = fmaf(bcast(p, 11), et[11], q3); \
      q0 = fmaf(bcast(p, 12), et[12], q0); q1 = fmaf(bcast(p, 13), et[13], q1); \
      q2 = fmaf(bcast(p, 14), et[14], q2); q3 = fmaf(bcast(p, 15), et[15], q3); \
      q0 = fmaf(bcast(p, 16), et[16], q0);                                \
      PN = ((q0 + q1) + (q2 + q3)) * (eem); }

#define CRF_STEP(eem)      { float pn_; CRF_BODY(eem, pn_); p = pn_; }
#define CRF_STEPG(eem, tt) { float pn_; CRF_BODY(eem, pn_); p = ((tt) < len) ? pn_ : p; }

__global__ __launch_bounds__(64) void crf_kernel(const float* __restrict__ emis,
                                                 const float* __restrict__ st_,
                                                 const float* __restrict__ en_,
                                                 const float* __restrict__ tr_,
                                                 const int* __restrict__ labels,
                                                 const int* __restrict__ mask,
                                                 float* __restrict__ llh) {
    const int b = blockIdx.x;
    const int l = threadIdx.x;
    const float* eb = emis + (size_t)b * TT * NL;
    const int*   lb = labels + b * TT;

    // ---- sequence length (prefix mask) ----
    int lenp = 0;
#pragma unroll
    for (int m = 0; m < 8; ++m) lenp += (mask[b * TT + l + 64 * m] != 0);
#pragma unroll
    for (int off = 32; off; off >>= 1) lenp += __shfl_down(lenp, off);
    const int len = __shfl(lenp, 0);

    // ---- numerator ----
    float np = 0.f;
#pragma unroll
    for (int m = 0; m < 8; ++m) {
        const int t = l + 64 * m;
        int tag = lb[t]; if ((unsigned)tag >= NL) tag = 0;
        if (t < len) {
            if (t == 0) {
                np += st_[tag] + eb[tag];
            } else {
                int tp = lb[t - 1]; if ((unsigned)tp >= NL) tp = 0;
                np += tr_[tp * NL + tag] + eb[t * NL + tag];
            }
            if (t == len - 1) np += en_[tag];
        }
    }
#pragma unroll
    for (int off = 32; off; off >>= 1) np += __shfl_down(np, off);
    const float num = __shfl(np, 0);

    // ---- denominator: exp-domain forward scan ----
    const bool act = (l < NL);
    const int  j   = act ? l : 0;

    float et[NL];
#pragma unroll
    for (int i = 0; i < NL; ++i) et[i] = act ? __expf(tr_[i * NL + j]) : 0.f;

    float p = act ? __expf(st_[j] + eb[j]) : 0.f;
    int   Mi = 0;

    float cur[8];
#pragma unroll
    for (int i = 0; i < 8; ++i) cur[i] = __expf(eb[(1 + i) * NL + j]);

    for (int t0 = 1; t0 < len; t0 += 8) {
        float nx[8];
#pragma unroll
        for (int i = 0; i < 8; ++i) {
            int tn = t0 + 8 + i; tn = (tn < TT) ? tn : (TT - 1);
            nx[i] = eb[tn * NL + j];             // issue; consumed next group
        }
        if (t0 + 8 <= len) {
            CRF_STEP(cur[0]); CRF_STEP(cur[1]); CRF_STEP(cur[2]); CRF_STEP(cur[3]);
            CRF_STEP(cur[4]); CRF_STEP(cur[5]); CRF_STEP(cur[6]); CRF_STEP(cur[7]);
        } else {
            CRF_STEPG(cur[0], t0 + 0); CRF_STEPG(cur[1], t0 + 1);
            CRF_STEPG(cur[2], t0 + 2); CRF_STEPG(cur[3], t0 + 3);
            CRF_STEPG(cur[4], t0 + 4); CRF_STEPG(cur[5], t0 + 5);
            CRF_STEPG(cur[6], t0 + 6); CRF_STEPG(cur[7], t0 + 7);
        }
        // renorm by p0 via exponent extraction (no log/rcp on critical path)
        const unsigned pb = (unsigned)__builtin_amdgcn_readlane((int)__float_as_uint(p), 0);
        const int e = (int)(pb >> 23) - 127;
        Mi += e;
        p = ldexpf(p, -e);
#pragma unroll
        for (int i = 0; i < 8; ++i) cur[i] = __expf(nx[i]);
    }

    float v = act ? p * __expf(en_[j]) : 0.f;
#pragma unroll
    for (int off = 32; off; off >>= 1) v += __shfl_down(v, off);

    if (l == 0) {
        const float denom = (float)Mi * 0.6931471805599453f + __logf(v);
        llh[b] = num - denom;
    }
}

// ===========================================================================
// Kernel 3: loss = -mean(llh)
// ===========================================================================
__global__ __launch_bounds__(64) void loss_kernel(const float* __restrict__ llh,
                                                  float* __restrict__ loss) {
    float v = llh[threadIdx.x];
#pragma unroll
    for (int off = 32; off; off >>= 1) v += __shfl_down(v, off);
    if (threadIdx.x == 0) loss[0] = -(v * (1.0f / BB));
}

// ===========================================================================
extern "C" void kernel_launch(void* const* d_in, const int* in_sizes, int n_in,
                              void* d_out, int out_size, void* d_ws, size_t ws_size,
                              hipStream_t stream) {
    const float* outputs = (const float*)d_in[0];
    const float* fc_w    = (const float*)d_in[1];
    const float* fc_b    = (const float*)d_in[2];
    const float* start_t = (const float*)d_in[3];
    const float* end_t   = (const float*)d_in[4];
    const float* trans   = (const float*)d_in[5];
    const int*   labels  = (const int*)d_in[6];
    const int*   mask    = (const int*)d_in[7];

    float* emis = (float*)d_out;
    float* loss = emis + (size_t)BB * TT * NL;
    float* llh  = (float*)d_ws;

    emis_kernel<<<(BB * TT) / 64, 512, 0, stream>>>(outputs, fc_w, fc_b, emis);
    crf_kernel<<<BB, 64, 0, stream>>>(emis, start_t, end_t, trans, labels, mask, llh);
    loss_kernel<<<1, 64, 0, stream>>>(llh, loss);
}